// Round 1
// baseline (2647.323 us; speedup 1.0000x reference)
//
#include <hip/hip_runtime.h>
#include <hip/hip_bf16.h>
#include <math.h>

#define N_NODES 100000
#define N_EDGES 1250000
#define D_IN    64
#define D_HID   64
#define N_CLS   40

// ---------------------------------------------------------------------------
// Scatter: for each edge e, agg[dst[e]] += feat[src[e]] (64 floats),
// optionally deg[dst[e]] += 1. 16 threads per edge, float4 per thread.
// ---------------------------------------------------------------------------
__global__ __launch_bounds__(256) void scatter_edges(
    const float* __restrict__ feat,
    const int* __restrict__ src,
    const int* __restrict__ dst,
    float* __restrict__ agg,
    float* __restrict__ deg,   // may be null
    int n_edges)
{
    int tid = blockIdx.x * blockDim.x + threadIdx.x;
    int e = tid >> 4;          // 16 threads per edge
    if (e >= n_edges) return;
    int c = (tid & 15) * 4;    // float chunk offset within the 64-wide row
    int s = src[e];
    int d = dst[e];
    const float4 v = *reinterpret_cast<const float4*>(feat + (size_t)s * 64 + c);
    float* a = agg + (size_t)d * 64 + c;
    atomicAdd(a + 0, v.x);
    atomicAdd(a + 1, v.y);
    atomicAdd(a + 2, v.z);
    atomicAdd(a + 3, v.w);
    if (deg != nullptr && (tid & 15) == 0) atomicAdd(deg + d, 1.0f);
}

// ---------------------------------------------------------------------------
// Layer 1: h = relu( (agg/deg) @ W_l + b + x @ W_r ),  64 -> 64
// One wave per node; lane j computes output channel j. Weights in LDS.
// ---------------------------------------------------------------------------
__global__ __launch_bounds__(256) void sage_layer1(
    const float* __restrict__ x,
    const float* __restrict__ agg,
    const float* __restrict__ deg,
    const float* __restrict__ W_l,   // [64,64] row-major (k, j)
    const float* __restrict__ b,     // [64]
    const float* __restrict__ W_r,   // [64,64]
    float* __restrict__ h,
    int n_nodes)
{
    __shared__ float sWl[64 * 64];
    __shared__ float sWr[64 * 64];
    __shared__ float sb[64];
    for (int i = threadIdx.x; i < 64 * 64; i += 256) {
        sWl[i] = W_l[i];
        sWr[i] = W_r[i];
    }
    if (threadIdx.x < 64) sb[threadIdx.x] = b[threadIdx.x];
    __syncthreads();

    const int lane   = threadIdx.x & 63;
    const int wave   = blockIdx.x * 4 + (threadIdx.x >> 6);
    const int nwaves = gridDim.x * 4;

    for (int node = wave; node < n_nodes; node += nwaves) {
        float dv = deg[node];
        dv = dv > 1.0f ? dv : 1.0f;
        float a  = agg[(size_t)node * 64 + lane] / dv;
        float xv = x[(size_t)node * 64 + lane];
        float acc = sb[lane];
        #pragma unroll
        for (int k = 0; k < 64; ++k) {
            float ak = __shfl(a, k);
            float xk = __shfl(xv, k);
            acc += ak * sWl[k * 64 + lane] + xk * sWr[k * 64 + lane];
        }
        h[(size_t)node * 64 + lane] = acc > 0.0f ? acc : 0.0f;
    }
}

// ---------------------------------------------------------------------------
// Layer 2 + log_softmax: o = (agg/deg) @ W_l + b + h @ W_r ; out = logsoftmax(o)
// 64 -> 40. One wave per node; lanes 0..39 hold the 40 classes.
// ---------------------------------------------------------------------------
__global__ __launch_bounds__(256) void sage_layer2(
    const float* __restrict__ h,
    const float* __restrict__ agg,
    const float* __restrict__ deg,
    const float* __restrict__ W_l,   // [64,40]
    const float* __restrict__ b,     // [40]
    const float* __restrict__ W_r,   // [64,40]
    float* __restrict__ out,
    int n_nodes)
{
    __shared__ float sWl[64 * 40];
    __shared__ float sWr[64 * 40];
    __shared__ float sb[40];
    for (int i = threadIdx.x; i < 64 * 40; i += 256) {
        sWl[i] = W_l[i];
        sWr[i] = W_r[i];
    }
    if (threadIdx.x < 40) sb[threadIdx.x] = b[threadIdx.x];
    __syncthreads();

    const int lane   = threadIdx.x & 63;
    const int wave   = blockIdx.x * 4 + (threadIdx.x >> 6);
    const int nwaves = gridDim.x * 4;

    for (int node = wave; node < n_nodes; node += nwaves) {
        float dv = deg[node];
        dv = dv > 1.0f ? dv : 1.0f;
        float a  = agg[(size_t)node * 64 + lane] / dv;
        float hv = h[(size_t)node * 64 + lane];
        float acc = (lane < N_CLS) ? sb[lane] : -INFINITY;
        #pragma unroll
        for (int k = 0; k < 64; ++k) {
            float ak = __shfl(a, k);
            float hk = __shfl(hv, k);
            if (lane < N_CLS)
                acc += ak * sWl[k * N_CLS + lane] + hk * sWr[k * N_CLS + lane];
        }
        // log_softmax over lanes 0..39 (lanes >=40 hold -inf / contribute 0)
        float m = acc;
        #pragma unroll
        for (int off = 32; off > 0; off >>= 1)
            m = fmaxf(m, __shfl_xor(m, off));
        float ex = (lane < N_CLS) ? expf(acc - m) : 0.0f;
        float ssum = ex;
        #pragma unroll
        for (int off = 32; off > 0; off >>= 1)
            ssum += __shfl_xor(ssum, off);
        float res = acc - m - logf(ssum);
        if (lane < N_CLS) out[(size_t)node * N_CLS + lane] = res;
    }
}

extern "C" void kernel_launch(void* const* d_in, const int* in_sizes, int n_in,
                              void* d_out, int out_size, void* d_ws, size_t ws_size,
                              hipStream_t stream)
{
    (void)in_sizes; (void)n_in; (void)out_size; (void)ws_size;

    const float* x    = (const float*)d_in[0];
    const int*   ei   = (const int*)d_in[1];      // [2, E] flat: src then dst
    const float* W1_l = (const float*)d_in[2];
    const float* b1   = (const float*)d_in[3];
    const float* W1_r = (const float*)d_in[4];
    const float* W2_l = (const float*)d_in[5];
    const float* b2   = (const float*)d_in[6];
    const float* W2_r = (const float*)d_in[7];
    float* out = (float*)d_out;

    const int* src = ei;
    const int* dst = ei + N_EDGES;

    // workspace layout (bytes):
    //   deg : [0, 400000)                       100000 f32
    //   agg : [1<<20, 1<<20 + 25.6MB)           100000*64 f32 (reused both layers)
    //   h   : [28<<20, 28<<20 + 25.6MB)         100000*64 f32
    char* ws = (char*)d_ws;
    float* deg = (float*)(ws);
    float* agg = (float*)(ws + (1u << 20));
    float* h   = (float*)(ws + (28u << 20));

    const size_t aggBytes = (size_t)N_NODES * 64 * sizeof(float);
    const size_t degBytes = (size_t)N_NODES * sizeof(float);

    // zero deg + agg
    hipMemsetAsync(deg, 0, degBytes, stream);
    hipMemsetAsync(agg, 0, aggBytes, stream);

    // scatter layer 1: agg += x[src], deg += 1
    {
        int threads = N_EDGES * 16;
        int blocks = (threads + 255) / 256;
        scatter_edges<<<blocks, 256, 0, stream>>>(x, src, dst, agg, deg, N_EDGES);
    }

    // layer 1: h = relu(agg/deg @ W1_l + b1 + x @ W1_r)
    sage_layer1<<<2048, 256, 0, stream>>>(x, agg, deg, W1_l, b1, W1_r, h, N_NODES);

    // re-zero agg, scatter layer 2: agg += h[src]
    hipMemsetAsync(agg, 0, aggBytes, stream);
    {
        int threads = N_EDGES * 16;
        int blocks = (threads + 255) / 256;
        scatter_edges<<<blocks, 256, 0, stream>>>(h, src, dst, agg, nullptr, N_EDGES);
    }

    // layer 2 + log_softmax -> out
    sage_layer2<<<2048, 256, 0, stream>>>(h, agg, deg, W2_l, b2, W2_r, out, N_NODES);
}

// Round 2
// 674.686 us; speedup vs baseline: 3.9238x; 3.9238x over previous
//
#include <hip/hip_runtime.h>
#include <hip/hip_bf16.h>
#include <math.h>

#define N_NODES 100000
#define N_EDGES 1250000
#define D_IN    64
#define D_HID   64
#define N_CLS   40

#define SCAN_NBLK ((N_NODES + 255) / 256)   // 391

// ---------------------------------------------------------------------------
// CSR build step 1: histogram of dst -> hist[node] (int counts)
// ---------------------------------------------------------------------------
__global__ __launch_bounds__(256) void hist_deg(
    const int* __restrict__ dst, int* __restrict__ hist, int n_edges)
{
    int e = blockIdx.x * blockDim.x + threadIdx.x;
    if (e < n_edges) atomicAdd(&hist[dst[e]], 1);
}

// ---------------------------------------------------------------------------
// CSR build step 2a: per-block sums of hist
// ---------------------------------------------------------------------------
__global__ __launch_bounds__(256) void scan_block_sums(
    const int* __restrict__ hist, int* __restrict__ partial, int n)
{
    __shared__ int s[256];
    int i = blockIdx.x * 256 + threadIdx.x;
    s[threadIdx.x] = (i < n) ? hist[i] : 0;
    __syncthreads();
    for (int off = 128; off > 0; off >>= 1) {
        if (threadIdx.x < off) s[threadIdx.x] += s[threadIdx.x + off];
        __syncthreads();
    }
    if (threadIdx.x == 0) partial[blockIdx.x] = s[0];
}

// ---------------------------------------------------------------------------
// CSR build step 2b: inclusive scan of the 391 partials (single block)
// ---------------------------------------------------------------------------
__global__ __launch_bounds__(512) void scan_partials(
    int* __restrict__ partial, int nblk)
{
    __shared__ int s[512];
    int t = threadIdx.x;
    s[t] = (t < nblk) ? partial[t] : 0;
    __syncthreads();
    for (int off = 1; off < 512; off <<= 1) {
        int u = (t >= off) ? s[t - off] : 0;
        __syncthreads();
        s[t] += u;
        __syncthreads();
    }
    if (t < nblk) partial[t] = s[t];   // inclusive
}

// ---------------------------------------------------------------------------
// CSR build step 2c: final exclusive scan -> row_ptr, cursor
// NOTE: hist and cursor may alias (block reads then writes only its own chunk)
// ---------------------------------------------------------------------------
__global__ __launch_bounds__(256) void scan_final(
    const int* __restrict__ hist, const int* __restrict__ partial_incl,
    int* __restrict__ row_ptr, int* __restrict__ cursor, int n, int n_edges)
{
    __shared__ int s[256];
    int t = threadIdx.x;
    int i = blockIdx.x * 256 + t;
    int v = (i < n) ? hist[i] : 0;
    s[t] = v;
    __syncthreads();
    for (int off = 1; off < 256; off <<= 1) {
        int u = (t >= off) ? s[t - off] : 0;
        __syncthreads();
        s[t] += u;
        __syncthreads();
    }
    int excl = s[t] - v;
    int base = (blockIdx.x > 0) ? partial_incl[blockIdx.x - 1] : 0;
    if (i < n) {
        row_ptr[i] = base + excl;
        cursor[i]  = base + excl;
    }
    if (i == 0) row_ptr[n] = n_edges;
}

// ---------------------------------------------------------------------------
// CSR build step 3: bucket-fill edge sources sorted by dst
// ---------------------------------------------------------------------------
__global__ __launch_bounds__(256) void fill_csr(
    const int* __restrict__ src, const int* __restrict__ dst,
    int* __restrict__ cursor, int* __restrict__ csr_src, int n_edges)
{
    int e = blockIdx.x * blockDim.x + threadIdx.x;
    if (e < n_edges) {
        int d = dst[e];
        int pos = atomicAdd(&cursor[d], 1);
        csr_src[pos] = src[e];
    }
}

// ---------------------------------------------------------------------------
// Layer 1 fused: gather-aggregate + h = relu(mean @ W_l + b + x @ W_r)
// One wave per node; lane j = channel j. Weights in LDS.
// ---------------------------------------------------------------------------
__global__ __launch_bounds__(256) void sage_layer1_fused(
    const float* __restrict__ x,
    const int* __restrict__ row_ptr,
    const int* __restrict__ csr_src,
    const float* __restrict__ W_l,   // [64,64] (k, j)
    const float* __restrict__ b,     // [64]
    const float* __restrict__ W_r,   // [64,64]
    float* __restrict__ h,
    int n_nodes)
{
    __shared__ float sWl[64 * 64];
    __shared__ float sWr[64 * 64];
    __shared__ float sb[64];
    for (int i = threadIdx.x; i < 64 * 64; i += 256) {
        sWl[i] = W_l[i];
        sWr[i] = W_r[i];
    }
    if (threadIdx.x < 64) sb[threadIdx.x] = b[threadIdx.x];
    __syncthreads();

    const int lane   = threadIdx.x & 63;
    const int wave   = blockIdx.x * 4 + (threadIdx.x >> 6);
    const int nwaves = gridDim.x * 4;

    for (int node = wave; node < n_nodes; node += nwaves) {
        const int n0 = row_ptr[node];
        const int n1 = row_ptr[node + 1];
        float accA = 0.0f;
        int i = n0;
        for (; i + 4 <= n1; i += 4) {
            int s0 = csr_src[i + 0];
            int s1 = csr_src[i + 1];
            int s2 = csr_src[i + 2];
            int s3 = csr_src[i + 3];
            float v0 = x[(size_t)s0 * 64 + lane];
            float v1 = x[(size_t)s1 * 64 + lane];
            float v2 = x[(size_t)s2 * 64 + lane];
            float v3 = x[(size_t)s3 * 64 + lane];
            accA += (v0 + v1) + (v2 + v3);
        }
        for (; i < n1; ++i) accA += x[(size_t)csr_src[i] * 64 + lane];

        int degi = n1 - n0;
        float dv = (float)(degi > 1 ? degi : 1);
        float a  = accA / dv;
        float xv = x[(size_t)node * 64 + lane];

        float acc = sb[lane];
        #pragma unroll
        for (int k = 0; k < 64; ++k) {
            float ak = __shfl(a, k);
            float xk = __shfl(xv, k);
            acc += ak * sWl[k * 64 + lane] + xk * sWr[k * 64 + lane];
        }
        h[(size_t)node * 64 + lane] = acc > 0.0f ? acc : 0.0f;
    }
}

// ---------------------------------------------------------------------------
// Layer 2 fused: gather-aggregate + o = mean @ W_l + b + h @ W_r; log_softmax
// ---------------------------------------------------------------------------
__global__ __launch_bounds__(256) void sage_layer2_fused(
    const float* __restrict__ h,
    const int* __restrict__ row_ptr,
    const int* __restrict__ csr_src,
    const float* __restrict__ W_l,   // [64,40]
    const float* __restrict__ b,     // [40]
    const float* __restrict__ W_r,   // [64,40]
    float* __restrict__ out,
    int n_nodes)
{
    __shared__ float sWl[64 * N_CLS];
    __shared__ float sWr[64 * N_CLS];
    __shared__ float sb[N_CLS];
    for (int i = threadIdx.x; i < 64 * N_CLS; i += 256) {
        sWl[i] = W_l[i];
        sWr[i] = W_r[i];
    }
    if (threadIdx.x < N_CLS) sb[threadIdx.x] = b[threadIdx.x];
    __syncthreads();

    const int lane   = threadIdx.x & 63;
    const int wave   = blockIdx.x * 4 + (threadIdx.x >> 6);
    const int nwaves = gridDim.x * 4;

    for (int node = wave; node < n_nodes; node += nwaves) {
        const int n0 = row_ptr[node];
        const int n1 = row_ptr[node + 1];
        float accA = 0.0f;
        int i = n0;
        for (; i + 4 <= n1; i += 4) {
            int s0 = csr_src[i + 0];
            int s1 = csr_src[i + 1];
            int s2 = csr_src[i + 2];
            int s3 = csr_src[i + 3];
            float v0 = h[(size_t)s0 * 64 + lane];
            float v1 = h[(size_t)s1 * 64 + lane];
            float v2 = h[(size_t)s2 * 64 + lane];
            float v3 = h[(size_t)s3 * 64 + lane];
            accA += (v0 + v1) + (v2 + v3);
        }
        for (; i < n1; ++i) accA += h[(size_t)csr_src[i] * 64 + lane];

        int degi = n1 - n0;
        float dv = (float)(degi > 1 ? degi : 1);
        float a  = accA / dv;
        float hv = h[(size_t)node * 64 + lane];

        float acc = (lane < N_CLS) ? sb[lane] : -INFINITY;
        #pragma unroll
        for (int k = 0; k < 64; ++k) {
            float ak = __shfl(a, k);
            float hk = __shfl(hv, k);
            if (lane < N_CLS)
                acc += ak * sWl[k * N_CLS + lane] + hk * sWr[k * N_CLS + lane];
        }
        // log_softmax over lanes 0..39
        float m = acc;
        #pragma unroll
        for (int off = 32; off > 0; off >>= 1)
            m = fmaxf(m, __shfl_xor(m, off));
        float ex = (lane < N_CLS) ? expf(acc - m) : 0.0f;
        float ssum = ex;
        #pragma unroll
        for (int off = 32; off > 0; off >>= 1)
            ssum += __shfl_xor(ssum, off);
        float res = acc - m - logf(ssum);
        if (lane < N_CLS) out[(size_t)node * N_CLS + lane] = res;
    }
}

extern "C" void kernel_launch(void* const* d_in, const int* in_sizes, int n_in,
                              void* d_out, int out_size, void* d_ws, size_t ws_size,
                              hipStream_t stream)
{
    (void)in_sizes; (void)n_in; (void)out_size; (void)ws_size;

    const float* x    = (const float*)d_in[0];
    const int*   ei   = (const int*)d_in[1];      // [2, E] flat: src row then dst row
    const float* W1_l = (const float*)d_in[2];
    const float* b1   = (const float*)d_in[3];
    const float* W1_r = (const float*)d_in[4];
    const float* W2_l = (const float*)d_in[5];
    const float* b2   = (const float*)d_in[6];
    const float* W2_r = (const float*)d_in[7];
    float* out = (float*)d_out;

    const int* src = ei;
    const int* dst = ei + N_EDGES;

    // workspace layout (bytes):
    //   row_ptr : [0, 400004)            int[N_NODES+1]
    //   cursor  : [512K, 512K+400000)    int[N_NODES]   (doubles as hist)
    //   partial : [1M, 1M+2048)          int[512]
    //   csr_src : [1M+4096, +5MB)        int[N_EDGES]
    //   h       : [8M, 8M+25.6MB)        float[N_NODES*64]
    char* ws = (char*)d_ws;
    int*   row_ptr = (int*)(ws);
    int*   cursor  = (int*)(ws + (512u << 10));
    int*   partial = (int*)(ws + (1u << 20));
    int*   csr_src = (int*)(ws + (1u << 20) + 4096);
    float* h       = (float*)(ws + (8u << 20));

    const int edge_blocks = (N_EDGES + 255) / 256;

    // 1. histogram of dst into cursor (used as hist)
    hipMemsetAsync(cursor, 0, (size_t)N_NODES * sizeof(int), stream);
    hist_deg<<<edge_blocks, 256, 0, stream>>>(dst, cursor, N_EDGES);

    // 2. exclusive scan -> row_ptr (and cursor = copy for bucket fill)
    scan_block_sums<<<SCAN_NBLK, 256, 0, stream>>>(cursor, partial, N_NODES);
    scan_partials<<<1, 512, 0, stream>>>(partial, SCAN_NBLK);
    scan_final<<<SCAN_NBLK, 256, 0, stream>>>(cursor, partial, row_ptr, cursor,
                                              N_NODES, N_EDGES);

    // 3. bucket-fill csr_src
    fill_csr<<<edge_blocks, 256, 0, stream>>>(src, dst, cursor, csr_src, N_EDGES);

    // 4. layer 1 fused (gather + GEMM + relu)
    sage_layer1_fused<<<1024, 256, 0, stream>>>(x, row_ptr, csr_src,
                                                W1_l, b1, W1_r, h, N_NODES);

    // 5. layer 2 fused (gather + GEMM + log_softmax)
    sage_layer2_fused<<<1024, 256, 0, stream>>>(h, row_ptr, csr_src,
                                                W2_l, b2, W2_r, out, N_NODES);
}

// Round 3
// 513.234 us; speedup vs baseline: 5.1581x; 1.3146x over previous
//
#include <hip/hip_runtime.h>
#include <hip/hip_bf16.h>
#include <math.h>

#define N_NODES 100000
#define N_EDGES 1250000
#define D_IN    64
#define D_HID   64
#define N_CLS   40

#define SCAN_NBLK ((N_NODES + 255) / 256)   // 391

// ---------------------------------------------------------------------------
// CSR build step 1: histogram of dst -> hist[node]
// ---------------------------------------------------------------------------
__global__ __launch_bounds__(256) void hist_deg(
    const int* __restrict__ dst, int* __restrict__ hist, int n_edges)
{
    int e = blockIdx.x * blockDim.x + threadIdx.x;
    if (e < n_edges) atomicAdd(&hist[dst[e]], 1);
}

__global__ __launch_bounds__(256) void scan_block_sums(
    const int* __restrict__ hist, int* __restrict__ partial, int n)
{
    __shared__ int s[256];
    int i = blockIdx.x * 256 + threadIdx.x;
    s[threadIdx.x] = (i < n) ? hist[i] : 0;
    __syncthreads();
    for (int off = 128; off > 0; off >>= 1) {
        if (threadIdx.x < off) s[threadIdx.x] += s[threadIdx.x + off];
        __syncthreads();
    }
    if (threadIdx.x == 0) partial[blockIdx.x] = s[0];
}

__global__ __launch_bounds__(512) void scan_partials(
    int* __restrict__ partial, int nblk)
{
    __shared__ int s[512];
    int t = threadIdx.x;
    s[t] = (t < nblk) ? partial[t] : 0;
    __syncthreads();
    for (int off = 1; off < 512; off <<= 1) {
        int u = (t >= off) ? s[t - off] : 0;
        __syncthreads();
        s[t] += u;
        __syncthreads();
    }
    if (t < nblk) partial[t] = s[t];   // inclusive
}

__global__ __launch_bounds__(256) void scan_final(
    const int* __restrict__ hist, const int* __restrict__ partial_incl,
    int* __restrict__ row_ptr, int* __restrict__ cursor, int n, int n_edges)
{
    __shared__ int s[256];
    int t = threadIdx.x;
    int i = blockIdx.x * 256 + t;
    int v = (i < n) ? hist[i] : 0;
    s[t] = v;
    __syncthreads();
    for (int off = 1; off < 256; off <<= 1) {
        int u = (t >= off) ? s[t - off] : 0;
        __syncthreads();
        s[t] += u;
        __syncthreads();
    }
    int excl = s[t] - v;
    int base = (blockIdx.x > 0) ? partial_incl[blockIdx.x - 1] : 0;
    if (i < n) {
        row_ptr[i] = base + excl;
        cursor[i]  = base + excl;
    }
    if (i == 0) row_ptr[n] = n_edges;
}

__global__ __launch_bounds__(256) void fill_csr(
    const int* __restrict__ src, const int* __restrict__ dst,
    int* __restrict__ cursor, int* __restrict__ csr_src, int n_edges)
{
    int e = blockIdx.x * blockDim.x + threadIdx.x;
    if (e < n_edges) {
        int d = dst[e];
        int pos = atomicAdd(&cursor[d], 1);
        csr_src[pos] = src[e];
    }
}

// ---------------------------------------------------------------------------
// Aggregation-table GEMM 1: y1 = x @ W1_l  -> bf16 [N][64]
// Wave per node (grid-stride); lane j = out channel j; broadcast via readlane.
// ---------------------------------------------------------------------------
__global__ __launch_bounds__(256) void gemm_agg1(
    const float* __restrict__ x, const float* __restrict__ W,  // [64][64]
    __hip_bfloat16* __restrict__ y, int n_nodes)
{
    __shared__ float sW[64 * 64];
    for (int i = threadIdx.x; i < 64 * 64; i += 256) sW[i] = W[i];
    __syncthreads();
    const int lane = threadIdx.x & 63;
    const int wave = blockIdx.x * 4 + (threadIdx.x >> 6);
    const int nw   = gridDim.x * 4;
    for (int node = wave; node < n_nodes; node += nw) {
        int xi = __float_as_int(x[(size_t)node * 64 + lane]);
        float acc = 0.0f;
        #pragma unroll
        for (int k = 0; k < 64; ++k)
            acc += __int_as_float(__builtin_amdgcn_readlane(xi, k)) * sW[k * 64 + lane];
        y[(size_t)node * 64 + lane] = __float2bfloat16(acc);
    }
}

// ---------------------------------------------------------------------------
// Aggregation-table GEMM 2: y2 = h @ W2_l -> bf16 [N][40]
// ---------------------------------------------------------------------------
__global__ __launch_bounds__(256) void gemm_agg2(
    const __hip_bfloat16* __restrict__ h, const float* __restrict__ W, // [64][40]
    __hip_bfloat16* __restrict__ y, int n_nodes)
{
    __shared__ float sW[64 * N_CLS];
    for (int i = threadIdx.x; i < 64 * N_CLS; i += 256) sW[i] = W[i];
    __syncthreads();
    const int lane = threadIdx.x & 63;
    const int wave = blockIdx.x * 4 + (threadIdx.x >> 6);
    const int nw   = gridDim.x * 4;
    for (int node = wave; node < n_nodes; node += nw) {
        int hi = __float_as_int((float)h[(size_t)node * 64 + lane]);
        float acc = 0.0f;
        #pragma unroll
        for (int k = 0; k < 64; ++k) {
            float s = __int_as_float(__builtin_amdgcn_readlane(hi, k));
            if (lane < N_CLS) acc += s * sW[k * N_CLS + lane];
        }
        if (lane < N_CLS) y[(size_t)node * N_CLS + lane] = __float2bfloat16(acc);
    }
}

// ---------------------------------------------------------------------------
// Gather 1: h[node] = relu( mean(y1[src]) + b1 + x[node] @ W1_r )  -> bf16
// Wave per node; edge indices vector-loaded then readlane-broadcast.
// ---------------------------------------------------------------------------
__global__ __launch_bounds__(256) void gather1(
    const float* __restrict__ x,
    const __hip_bfloat16* __restrict__ y1,
    const float* __restrict__ Wr,   // [64][64]
    const float* __restrict__ b,    // [64]
    const int* __restrict__ row_ptr, const int* __restrict__ csr_src,
    __hip_bfloat16* __restrict__ h, int n_nodes)
{
    __shared__ float sW[64 * 64];
    for (int i = threadIdx.x; i < 64 * 64; i += 256) sW[i] = Wr[i];
    __syncthreads();
    const int lane = threadIdx.x & 63;
    const int wave = blockIdx.x * 4 + (threadIdx.x >> 6);
    const int nw   = gridDim.x * 4;
    const float bv = b[lane];

    for (int node = wave; node < n_nodes; node += nw) {
        const int n0 = row_ptr[node];
        const int n1 = row_ptr[node + 1];
        const int deg = n1 - n0;
        float acc = 0.0f;
        int base = n0, rem = deg;
        while (rem > 0) {
            int cnt = rem < 64 ? rem : 64;
            int idx = csr_src[base + lane];   // slack allocated past N_EDGES
            int e = 0;
            for (; e + 4 <= cnt; e += 4) {
                int s0 = __builtin_amdgcn_readlane(idx, e + 0);
                int s1 = __builtin_amdgcn_readlane(idx, e + 1);
                int s2 = __builtin_amdgcn_readlane(idx, e + 2);
                int s3 = __builtin_amdgcn_readlane(idx, e + 3);
                float v0 = (float)y1[(size_t)s0 * 64 + lane];
                float v1 = (float)y1[(size_t)s1 * 64 + lane];
                float v2 = (float)y1[(size_t)s2 * 64 + lane];
                float v3 = (float)y1[(size_t)s3 * 64 + lane];
                acc += (v0 + v1) + (v2 + v3);
            }
            for (; e < cnt; ++e) {
                int s = __builtin_amdgcn_readlane(idx, e);
                acc += (float)y1[(size_t)s * 64 + lane];
            }
            base += cnt; rem -= cnt;
        }
        // root term: x[node] @ W1_r
        int xi = __float_as_int(x[(size_t)node * 64 + lane]);
        float root = 0.0f;
        #pragma unroll
        for (int k = 0; k < 64; ++k)
            root += __int_as_float(__builtin_amdgcn_readlane(xi, k)) * sW[k * 64 + lane];

        float dv = (float)(deg > 1 ? deg : 1);
        float r = acc / dv + bv + root;
        h[(size_t)node * 64 + lane] = __float2bfloat16(r > 0.0f ? r : 0.0f);
    }
}

// ---------------------------------------------------------------------------
// Gather 2: out[node] = logsoftmax( mean(y2[src]) + b2 + h[node] @ W2_r )
// ---------------------------------------------------------------------------
__global__ __launch_bounds__(256) void gather2(
    const __hip_bfloat16* __restrict__ h,
    const __hip_bfloat16* __restrict__ y2,
    const float* __restrict__ Wr,   // [64][40]
    const float* __restrict__ b,    // [40]
    const int* __restrict__ row_ptr, const int* __restrict__ csr_src,
    float* __restrict__ out, int n_nodes)
{
    __shared__ float sW[64 * N_CLS];
    for (int i = threadIdx.x; i < 64 * N_CLS; i += 256) sW[i] = Wr[i];
    __syncthreads();
    const int lane = threadIdx.x & 63;
    const int wave = blockIdx.x * 4 + (threadIdx.x >> 6);
    const int nw   = gridDim.x * 4;
    const float bv = (lane < N_CLS) ? b[lane] : 0.0f;

    for (int node = wave; node < n_nodes; node += nw) {
        const int n0 = row_ptr[node];
        const int n1 = row_ptr[node + 1];
        const int deg = n1 - n0;
        float acc = 0.0f;
        int base = n0, rem = deg;
        while (rem > 0) {
            int cnt = rem < 64 ? rem : 64;
            int idx = csr_src[base + lane];
            int e = 0;
            for (; e + 4 <= cnt; e += 4) {
                int s0 = __builtin_amdgcn_readlane(idx, e + 0);
                int s1 = __builtin_amdgcn_readlane(idx, e + 1);
                int s2 = __builtin_amdgcn_readlane(idx, e + 2);
                int s3 = __builtin_amdgcn_readlane(idx, e + 3);
                if (lane < N_CLS) {
                    float v0 = (float)y2[(size_t)s0 * N_CLS + lane];
                    float v1 = (float)y2[(size_t)s1 * N_CLS + lane];
                    float v2 = (float)y2[(size_t)s2 * N_CLS + lane];
                    float v3 = (float)y2[(size_t)s3 * N_CLS + lane];
                    acc += (v0 + v1) + (v2 + v3);
                }
            }
            for (; e < cnt; ++e) {
                int s = __builtin_amdgcn_readlane(idx, e);
                if (lane < N_CLS) acc += (float)y2[(size_t)s * N_CLS + lane];
            }
            base += cnt; rem -= cnt;
        }
        // root term: h[node] @ W2_r
        int hi = __float_as_int((float)h[(size_t)node * 64 + lane]);
        float root = 0.0f;
        #pragma unroll
        for (int k = 0; k < 64; ++k) {
            float s = __int_as_float(__builtin_amdgcn_readlane(hi, k));
            if (lane < N_CLS) root += s * sW[k * N_CLS + lane];
        }

        float dv = (float)(deg > 1 ? deg : 1);
        float logit = (lane < N_CLS) ? (acc / dv + bv + root) : -INFINITY;

        float m = logit;
        #pragma unroll
        for (int off = 32; off > 0; off >>= 1)
            m = fmaxf(m, __shfl_xor(m, off));
        float ex = (lane < N_CLS) ? expf(logit - m) : 0.0f;
        float ssum = ex;
        #pragma unroll
        for (int off = 32; off > 0; off >>= 1)
            ssum += __shfl_xor(ssum, off);
        float res = logit - m - logf(ssum);
        if (lane < N_CLS) out[(size_t)node * N_CLS + lane] = res;
    }
}

extern "C" void kernel_launch(void* const* d_in, const int* in_sizes, int n_in,
                              void* d_out, int out_size, void* d_ws, size_t ws_size,
                              hipStream_t stream)
{
    (void)in_sizes; (void)n_in; (void)out_size; (void)ws_size;

    const float* x    = (const float*)d_in[0];
    const int*   ei   = (const int*)d_in[1];      // [2, E]: src row, then dst row
    const float* W1_l = (const float*)d_in[2];
    const float* b1   = (const float*)d_in[3];
    const float* W1_r = (const float*)d_in[4];
    const float* W2_l = (const float*)d_in[5];
    const float* b2   = (const float*)d_in[6];
    const float* W2_r = (const float*)d_in[7];
    float* out = (float*)d_out;

    const int* src = ei;
    const int* dst = ei + N_EDGES;

    // workspace layout (bytes):
    //   row_ptr : [0, 400004)                 int[N+1]
    //   cursor  : [512K, 512K+400000)         int[N] (doubles as hist)
    //   partial : [1M, 1M+2048)               int[512]
    //   csr_src : [1M+4K, +5MB+256)           int[N_EDGES+64] (slack for vec load)
    //   y1 / y2 : [8M, 8M+12.8MB)             bf16[N*64] (y2 bf16[N*40] overlays)
    //   h       : [21M, 21M+12.8MB)           bf16[N*64]
    char* ws = (char*)d_ws;
    int*            row_ptr = (int*)(ws);
    int*            cursor  = (int*)(ws + (512u << 10));
    int*            partial = (int*)(ws + (1u << 20));
    int*            csr_src = (int*)(ws + (1u << 20) + 4096);
    __hip_bfloat16* y1      = (__hip_bfloat16*)(ws + (8u << 20));
    __hip_bfloat16* y2      = (__hip_bfloat16*)(ws + (8u << 20));
    __hip_bfloat16* h       = (__hip_bfloat16*)(ws + (21u << 20));

    const int edge_blocks = (N_EDGES + 255) / 256;

    // CSR build
    hipMemsetAsync(cursor, 0, (size_t)N_NODES * sizeof(int), stream);
    hist_deg<<<edge_blocks, 256, 0, stream>>>(dst, cursor, N_EDGES);
    scan_block_sums<<<SCAN_NBLK, 256, 0, stream>>>(cursor, partial, N_NODES);
    scan_partials<<<1, 512, 0, stream>>>(partial, SCAN_NBLK);
    scan_final<<<SCAN_NBLK, 256, 0, stream>>>(cursor, partial, row_ptr, cursor,
                                              N_NODES, N_EDGES);
    fill_csr<<<edge_blocks, 256, 0, stream>>>(src, dst, cursor, csr_src, N_EDGES);

    // layer 1: table GEMM, then gather+root+relu
    gemm_agg1<<<1024, 256, 0, stream>>>(x, W1_l, y1, N_NODES);
    gather1<<<2048, 256, 0, stream>>>(x, y1, W1_r, b1, row_ptr, csr_src, h, N_NODES);

    // layer 2: table GEMM, then gather+root+log_softmax
    gemm_agg2<<<1024, 256, 0, stream>>>(h, W2_l, y2, N_NODES);
    gather2<<<2048, 256, 0, stream>>>(h, y2, W2_r, b2, row_ptr, csr_src, out, N_NODES);
}

// Round 4
// 449.172 us; speedup vs baseline: 5.8938x; 1.1426x over previous
//
#include <hip/hip_runtime.h>
#include <hip/hip_bf16.h>
#include <math.h>

#define N_NODES 100000
#define N_EDGES 1250000
#define D_IN    64
#define D_HID   64
#define N_CLS   40

#define SCAN_NBLK ((N_NODES + 255) / 256)   // 391

typedef unsigned int uint;

static __device__ __forceinline__ uint pack_bf16x2(float a, float b) {
    unsigned short ua = __builtin_bit_cast(unsigned short, __float2bfloat16(a));
    unsigned short ub = __builtin_bit_cast(unsigned short, __float2bfloat16(b));
    return (uint)ua | ((uint)ub << 16);
}

// ---------------------------------------------------------------------------
// CSR build (unchanged from round 3)
// ---------------------------------------------------------------------------
__global__ __launch_bounds__(256) void hist_deg(
    const int* __restrict__ dst, int* __restrict__ hist, int n_edges)
{
    int e = blockIdx.x * blockDim.x + threadIdx.x;
    if (e < n_edges) atomicAdd(&hist[dst[e]], 1);
}

__global__ __launch_bounds__(256) void scan_block_sums(
    const int* __restrict__ hist, int* __restrict__ partial, int n)
{
    __shared__ int s[256];
    int i = blockIdx.x * 256 + threadIdx.x;
    s[threadIdx.x] = (i < n) ? hist[i] : 0;
    __syncthreads();
    for (int off = 128; off > 0; off >>= 1) {
        if (threadIdx.x < off) s[threadIdx.x] += s[threadIdx.x + off];
        __syncthreads();
    }
    if (threadIdx.x == 0) partial[blockIdx.x] = s[0];
}

__global__ __launch_bounds__(512) void scan_partials(
    int* __restrict__ partial, int nblk)
{
    __shared__ int s[512];
    int t = threadIdx.x;
    s[t] = (t < nblk) ? partial[t] : 0;
    __syncthreads();
    for (int off = 1; off < 512; off <<= 1) {
        int u = (t >= off) ? s[t - off] : 0;
        __syncthreads();
        s[t] += u;
        __syncthreads();
    }
    if (t < nblk) partial[t] = s[t];   // inclusive
}

__global__ __launch_bounds__(256) void scan_final(
    const int* __restrict__ hist, const int* __restrict__ partial_incl,
    int* __restrict__ row_ptr, int* __restrict__ cursor, int n, int n_edges)
{
    __shared__ int s[256];
    int t = threadIdx.x;
    int i = blockIdx.x * 256 + t;
    int v = (i < n) ? hist[i] : 0;
    s[t] = v;
    __syncthreads();
    for (int off = 1; off < 256; off <<= 1) {
        int u = (t >= off) ? s[t - off] : 0;
        __syncthreads();
        s[t] += u;
        __syncthreads();
    }
    int excl = s[t] - v;
    int base = (blockIdx.x > 0) ? partial_incl[blockIdx.x - 1] : 0;
    if (i < n) {
        row_ptr[i] = base + excl;
        cursor[i]  = base + excl;
    }
    if (i == 0) row_ptr[n] = n_edges;
}

__global__ __launch_bounds__(256) void fill_csr(
    const int* __restrict__ src, const int* __restrict__ dst,
    int* __restrict__ cursor, int* __restrict__ csr_src, int n_edges)
{
    int e = blockIdx.x * blockDim.x + threadIdx.x;
    if (e < n_edges) {
        int d = dst[e];
        int pos = atomicAdd(&cursor[d], 1);
        csr_src[pos] = src[e];
    }
}

// ---------------------------------------------------------------------------
// Table GEMM 1: y1 = bf16(x @ W1_l), weights held in 64 VGPRs per lane.
// ---------------------------------------------------------------------------
__global__ __launch_bounds__(256, 4) void gemm_y1(
    const float* __restrict__ x, const float* __restrict__ W,  // [64][64]
    __hip_bfloat16* __restrict__ y, int n_nodes)
{
    const int lane = threadIdx.x & 63;
    float wl[64];
    #pragma unroll
    for (int k = 0; k < 64; ++k) wl[k] = W[k * 64 + lane];

    const int wave = blockIdx.x * 4 + (threadIdx.x >> 6);
    const int nw   = gridDim.x * 4;
    for (int node = wave; node < n_nodes; node += nw) {
        int xi = __float_as_int(x[(size_t)node * 64 + lane]);
        float acc = 0.0f;
        #pragma unroll
        for (int k = 0; k < 64; ++k)
            acc += __int_as_float(__builtin_amdgcn_readlane(xi, k)) * wl[k];
        y[(size_t)node * 64 + lane] = __float2bfloat16(acc);
    }
}

// ---------------------------------------------------------------------------
// Table GEMM 2: y2 = bf16(h @ W2_l)   (64 -> 40, lanes >= 40 idle on store)
// ---------------------------------------------------------------------------
__global__ __launch_bounds__(256, 4) void gemm_y2(
    const __hip_bfloat16* __restrict__ h, const float* __restrict__ W, // [64][40]
    __hip_bfloat16* __restrict__ y, int n_nodes)
{
    const int lane = threadIdx.x & 63;
    const int cl = lane < N_CLS ? lane : N_CLS - 1;
    float wl[64];
    #pragma unroll
    for (int k = 0; k < 64; ++k) wl[k] = W[k * N_CLS + cl];

    const int wave = blockIdx.x * 4 + (threadIdx.x >> 6);
    const int nw   = gridDim.x * 4;
    for (int node = wave; node < n_nodes; node += nw) {
        int hi = __float_as_int((float)h[(size_t)node * 64 + lane]);
        float acc = 0.0f;
        #pragma unroll
        for (int k = 0; k < 64; ++k)
            acc += __int_as_float(__builtin_amdgcn_readlane(hi, k)) * wl[k];
        if (lane < N_CLS)
            y[(size_t)node * N_CLS + lane] = __float2bfloat16(acc);
    }
}

// ---------------------------------------------------------------------------
// Gather 1: h = relu( mean(y1[src]) + b1 + x@W1_r ).
// 4 edges per wave-load: 16 lanes x 8 B per 128 B row; edge index picked by
// ds_bpermute from the 64-wide index vector. Dummy row N_NODES is zero.
// Root GEMM from VGPR weights; quad-layout reconcile via ds_bpermute.
// ---------------------------------------------------------------------------
__global__ __launch_bounds__(256, 4) void gather1(
    const float* __restrict__ x,
    const __hip_bfloat16* __restrict__ y1,   // [N+1][64], row N zeroed
    const float* __restrict__ Wr,            // [64][64]
    const float* __restrict__ b,             // [64]
    const int* __restrict__ row_ptr, const int* __restrict__ csr_src,
    __hip_bfloat16* __restrict__ h, int n_nodes)
{
    const int lane = threadIdx.x & 63;
    float wr[64];
    #pragma unroll
    for (int k = 0; k < 64; ++k) wr[k] = Wr[k * 64 + lane];
    const float bv = b[lane];

    const int q4  = (lane >> 4) * 4;      // bpermute byte-sel for quad id
    const int pre = (lane & 15) * 8;      // byte offset within 128 B row
    const int t16 = (lane & 15) * 16;     // transpose bpermute base
    const char* y1c = (const char*)y1;

    const int wave = blockIdx.x * 4 + (threadIdx.x >> 6);
    const int nw   = gridDim.x * 4;

    for (int node = wave; node < n_nodes; node += nw) {
        const int n0  = row_ptr[node];
        const int deg = row_ptr[node + 1] - n0;
        float a0 = 0.f, a1 = 0.f, a2 = 0.f, a3 = 0.f;
        int base = n0, rem = deg;
        while (rem > 0) {
            int cnt = rem < 64 ? rem : 64;
            int idx = csr_src[base + lane];          // slack past N_EDGES
            if (lane >= cnt) idx = n_nodes;          // -> zero dummy row
            int groups = (cnt + 7) & ~7;             // round to 8 edges
            for (int e = 0; e < groups; e += 8) {
                int sel0 = __builtin_amdgcn_ds_bpermute(e * 4 + q4, idx);
                int sel1 = __builtin_amdgcn_ds_bpermute(e * 4 + 16 + q4, idx);
                uint2 d0 = *(const uint2*)(y1c + ((size_t)(uint)sel0 * 128u + (uint)pre));
                uint2 d1 = *(const uint2*)(y1c + ((size_t)(uint)sel1 * 128u + (uint)pre));
                a0 += __uint_as_float(d0.x << 16);
                a1 += __uint_as_float(d0.x & 0xffff0000u);
                a2 += __uint_as_float(d0.y << 16);
                a3 += __uint_as_float(d0.y & 0xffff0000u);
                a0 += __uint_as_float(d1.x << 16);
                a1 += __uint_as_float(d1.x & 0xffff0000u);
                a2 += __uint_as_float(d1.y << 16);
                a3 += __uint_as_float(d1.y & 0xffff0000u);
            }
            base += cnt; rem -= cnt;
        }
        // reduce the 4 quad replicas
        a0 += __shfl_xor(a0, 16); a0 += __shfl_xor(a0, 32);
        a1 += __shfl_xor(a1, 16); a1 += __shfl_xor(a1, 32);
        a2 += __shfl_xor(a2, 16); a2 += __shfl_xor(a2, 32);
        a3 += __shfl_xor(a3, 16); a3 += __shfl_xor(a3, 32);

        // root: channel=lane layout, bias folded in
        int xi = __float_as_int(x[(size_t)node * 64 + lane]);
        float root = bv;
        #pragma unroll
        for (int k = 0; k < 64; ++k)
            root += __int_as_float(__builtin_amdgcn_readlane(xi, k)) * wr[k];

        // transpose root to quad layout (channels 4*(lane&15)+j)
        float r0 = __int_as_float(__builtin_amdgcn_ds_bpermute(t16 +  0, __float_as_int(root)));
        float r1 = __int_as_float(__builtin_amdgcn_ds_bpermute(t16 +  4, __float_as_int(root)));
        float r2 = __int_as_float(__builtin_amdgcn_ds_bpermute(t16 +  8, __float_as_int(root)));
        float r3 = __int_as_float(__builtin_amdgcn_ds_bpermute(t16 + 12, __float_as_int(root)));

        float inv = 1.0f / (float)(deg > 1 ? deg : 1);
        float v0 = a0 * inv + r0; v0 = v0 > 0.f ? v0 : 0.f;
        float v1 = a1 * inv + r1; v1 = v1 > 0.f ? v1 : 0.f;
        float v2 = a2 * inv + r2; v2 = v2 > 0.f ? v2 : 0.f;
        float v3 = a3 * inv + r3; v3 = v3 > 0.f ? v3 : 0.f;

        if (lane < 16) {
            uint2 o;
            o.x = pack_bf16x2(v0, v1);
            o.y = pack_bf16x2(v2, v3);
            *(uint2*)((char*)h + ((size_t)node * 128u + (uint)pre)) = o;
        }
    }
}

// ---------------------------------------------------------------------------
// Gather 2: out = logsoftmax( mean(y2[src]) + b2 + h@W2_r ).
// 2 edges per wave-load: 20 of each 32 lanes x dword on 80 B rows (lanes
// 20..31 load a duplicate dword, results unused). Root from VGPR weights.
// ---------------------------------------------------------------------------
__global__ __launch_bounds__(256, 4) void gather2(
    const __hip_bfloat16* __restrict__ h,
    const __hip_bfloat16* __restrict__ y2,   // [N+1][40], row N zeroed
    const float* __restrict__ Wr,            // [64][40]
    const float* __restrict__ b,             // [40]
    const int* __restrict__ row_ptr, const int* __restrict__ csr_src,
    float* __restrict__ out, int n_nodes)
{
    const int lane  = threadIdx.x & 63;
    const int cl    = lane < N_CLS ? lane : N_CLS - 1;
    float wr[64];
    #pragma unroll
    for (int k = 0; k < 64; ++k) wr[k] = Wr[k * N_CLS + cl];
    const float bv = b[cl];

    const int lpair = lane & 31;                    // 0..31; active < 20
    const int p2    = (lane >> 5) * 4;              // bpermute sel: half id
    const int pre2  = (lpair < 20 ? lpair : 19) * 4;  // byte off in 80 B row
    const int s0sel = (2 * lpair < 62 ? 2 * lpair : 62) * 4;
    const char* y2c = (const char*)y2;

    const int wave = blockIdx.x * 4 + (threadIdx.x >> 6);
    const int nw   = gridDim.x * 4;

    for (int node = wave; node < n_nodes; node += nw) {
        const int n0  = row_ptr[node];
        const int deg = row_ptr[node + 1] - n0;
        float a0 = 0.f, a1 = 0.f;
        int base = n0, rem = deg;
        while (rem > 0) {
            int cnt = rem < 64 ? rem : 64;
            int idx = csr_src[base + lane];
            if (lane >= cnt) idx = n_nodes;
            int groups = (cnt + 3) & ~3;            // round to 4 edges
            for (int e = 0; e < groups; e += 4) {
                int sel0 = __builtin_amdgcn_ds_bpermute(e * 4 + p2, idx);
                int sel1 = __builtin_amdgcn_ds_bpermute(e * 4 + 8 + p2, idx);
                uint d0 = *(const uint*)(y2c + ((size_t)(uint)sel0 * 80u + (uint)pre2));
                uint d1 = *(const uint*)(y2c + ((size_t)(uint)sel1 * 80u + (uint)pre2));
                a0 += __uint_as_float(d0 << 16);
                a1 += __uint_as_float(d0 & 0xffff0000u);
                a0 += __uint_as_float(d1 << 16);
                a1 += __uint_as_float(d1 & 0xffff0000u);
            }
            base += cnt; rem -= cnt;
        }
        a0 += __shfl_xor(a0, 32);
        a1 += __shfl_xor(a1, 32);

        // root: channel=lane (lanes >= 40 duplicate ch 39; unused)
        int hi = __float_as_int((float)h[(size_t)node * 64 + lane]);
        float root = bv;
        #pragma unroll
        for (int k = 0; k < 64; ++k)
            root += __int_as_float(__builtin_amdgcn_readlane(hi, k)) * wr[k];

        // transpose to pair layout: channels 2*lpair, 2*lpair+1
        float r0 = __int_as_float(__builtin_amdgcn_ds_bpermute(s0sel,     __float_as_int(root)));
        float r1 = __int_as_float(__builtin_amdgcn_ds_bpermute(s0sel + 4, __float_as_int(root)));

        float inv = 1.0f / (float)(deg > 1 ? deg : 1);
        float l0 = a0 * inv + r0;
        float l1 = a1 * inv + r1;
        if (lpair >= 20) { l0 = -INFINITY; l1 = -INFINITY; }

        float m = fmaxf(l0, l1);
        #pragma unroll
        for (int off = 16; off > 0; off >>= 1)
            m = fmaxf(m, __shfl_xor(m, off));
        float ex = (lpair < 20) ? (expf(l0 - m) + expf(l1 - m)) : 0.0f;
        #pragma unroll
        for (int off = 16; off > 0; off >>= 1)
            ex += __shfl_xor(ex, off);
        float lg = m + logf(ex);
        if (lane < 20) {
            float2 o = make_float2(l0 - lg, l1 - lg);
            *(float2*)(out + (size_t)node * N_CLS + lpair * 2) = o;
        }
    }
}

extern "C" void kernel_launch(void* const* d_in, const int* in_sizes, int n_in,
                              void* d_out, int out_size, void* d_ws, size_t ws_size,
                              hipStream_t stream)
{
    (void)in_sizes; (void)n_in; (void)out_size; (void)ws_size;

    const float* x    = (const float*)d_in[0];
    const int*   ei   = (const int*)d_in[1];      // [2, E]: src row, then dst row
    const float* W1_l = (const float*)d_in[2];
    const float* b1   = (const float*)d_in[3];
    const float* W1_r = (const float*)d_in[4];
    const float* W2_l = (const float*)d_in[5];
    const float* b2   = (const float*)d_in[6];
    const float* W2_r = (const float*)d_in[7];
    float* out = (float*)d_out;

    const int* src = ei;
    const int* dst = ei + N_EDGES;

    // workspace layout (bytes):
    //   row_ptr : [0, 400004)                 int[N+1]
    //   cursor  : [512K, 512K+400000)         int[N] (doubles as hist)
    //   partial : [1M, 1M+2048)               int[512]
    //   csr_src : [1M+4K, +5MB+256)           int[N_EDGES+64] (slack)
    //   y1 / y2 : [8M, 8M+12.8MB+128)         bf16[(N+1)*64]; y2 bf16[(N+1)*40] overlays
    //   h       : [21M, 21M+12.8MB)           bf16[N*64]
    char* ws = (char*)d_ws;
    int*            row_ptr = (int*)(ws);
    int*            cursor  = (int*)(ws + (512u << 10));
    int*            partial = (int*)(ws + (1u << 20));
    int*            csr_src = (int*)(ws + (1u << 20) + 4096);
    __hip_bfloat16* y1      = (__hip_bfloat16*)(ws + (8u << 20));
    __hip_bfloat16* y2      = (__hip_bfloat16*)(ws + (8u << 20));
    __hip_bfloat16* h       = (__hip_bfloat16*)(ws + (21u << 20));

    const int edge_blocks = (N_EDGES + 255) / 256;

    // CSR build
    hipMemsetAsync(cursor, 0, (size_t)N_NODES * sizeof(int), stream);
    hist_deg<<<edge_blocks, 256, 0, stream>>>(dst, cursor, N_EDGES);
    scan_block_sums<<<SCAN_NBLK, 256, 0, stream>>>(cursor, partial, N_NODES);
    scan_partials<<<1, 512, 0, stream>>>(partial, SCAN_NBLK);
    scan_final<<<SCAN_NBLK, 256, 0, stream>>>(cursor, partial, row_ptr, cursor,
                                              N_NODES, N_EDGES);
    fill_csr<<<edge_blocks, 256, 0, stream>>>(src, dst, cursor, csr_src, N_EDGES);

    // layer 1
    hipMemsetAsync(y1 + (size_t)N_NODES * 64, 0, 64 * sizeof(__hip_bfloat16), stream);
    gemm_y1<<<1024, 256, 0, stream>>>(x, W1_l, y1, N_NODES);
    gather1<<<1024, 256, 0, stream>>>(x, y1, W1_r, b1, row_ptr, csr_src, h, N_NODES);

    // layer 2 (y2 overlays y1's region -> zero its dummy row after gather1)
    hipMemsetAsync(y2 + (size_t)N_NODES * N_CLS, 0, N_CLS * sizeof(__hip_bfloat16), stream);
    gemm_y2<<<1024, 256, 0, stream>>>(h, W2_l, y2, N_NODES);
    gather2<<<1024, 256, 0, stream>>>(h, y2, W2_r, b2, row_ptr, csr_src, out, N_NODES);
}